// Round 1
// baseline (1986.743 us; speedup 1.0000x reference)
//
#include <hip/hip_runtime.h>
#include <math.h>

#define VERY_NEG  -100000000000.0f
#define VERY_SMALLF 1e-10f

constexpr int B  = 8;
constexpr int E  = 2000;
constexpr int FC = 12000;
constexpr int Q  = 20;
constexpr int WD = 300;
constexpr int D  = 100;
constexpr int NW = 40000;
constexpr int NE = 100000;
constexpr int G4 = 4 * D;   // 400
constexpr int NREL = 301;

__device__ __forceinline__ float sigmoidf_(float x) { return 1.0f / (1.0f + expf(-x)); }

// rel_proj[r,d] = rel_emb[r,:] . rel_W[d,:] + rel_b[d]    (301 x 100, K=600)
__global__ void k_rel_proj(const float* __restrict__ rel_emb, const float* __restrict__ rel_W,
                           const float* __restrict__ rel_b, float* __restrict__ rel_proj) {
    __shared__ float row[2 * WD];
    int r = blockIdx.x;
    for (int k = threadIdx.x; k < 2 * WD; k += blockDim.x) row[k] = rel_emb[r * 2 * WD + k];
    __syncthreads();
    int d = threadIdx.x;
    if (d < D) {
        float acc = rel_b[d];
        for (int k = 0; k < 2 * WD; ++k) acc += row[k] * rel_W[d * 2 * WD + k];
        rel_proj[r * D + d] = acc;
    }
}

// self_proj[l,r,d] = rel_proj[r,:] . self_W[l,d,:] + self_b[l,d]
__global__ void k_self_proj(const float* __restrict__ rel_proj, const float* __restrict__ self_W,
                            const float* __restrict__ self_b, float* __restrict__ self_proj) {
    __shared__ float row[D];
    int r = blockIdx.x, l = blockIdx.y;
    for (int k = threadIdx.x; k < D; k += blockDim.x) row[k] = rel_proj[r * D + k];
    __syncthreads();
    int d = threadIdx.x;
    if (d < D) {
        float acc = self_b[l * D + d];
        for (int k = 0; k < D; ++k) acc += row[k] * self_W[l * D * D + d * D + k];
        self_proj[(l * NREL + r) * D + d] = acc;
    }
}

// xW[bt,g] = word_emb[qtext[bt],:] . Wih[g,:] + bih[g] + bhh[g]
__global__ void k_xw(const int* __restrict__ qtext, const float* __restrict__ word_emb,
                     const float* __restrict__ Wih, const float* __restrict__ bih,
                     const float* __restrict__ bhh, float* __restrict__ xW) {
    __shared__ float row[WD];
    int bt = blockIdx.x;
    int w = qtext[bt];
    for (int k = threadIdx.x; k < WD; k += blockDim.x) row[k] = word_emb[w * WD + k];
    __syncthreads();
    for (int g = threadIdx.x; g < G4; g += blockDim.x) {
        float acc = bih[g] + bhh[g];
        for (int k = 0; k < WD; ++k) acc += row[k] * Wih[g * WD + k];
        xW[bt * G4 + g] = acc;
    }
}

// recurrent LSTM, one block per batch element
__global__ void k_lstm(const float* __restrict__ xW, const float* __restrict__ Whh,
                       float* __restrict__ qh) {
    __shared__ float h[D], c[D], gate[G4];
    int b = blockIdx.x;
    if (threadIdx.x < D) { h[threadIdx.x] = 0.f; c[threadIdx.x] = 0.f; }
    __syncthreads();
    for (int t = 0; t < Q; ++t) {
        int g = threadIdx.x;
        if (g < G4) {
            float acc = xW[(b * Q + t) * G4 + g];
            for (int k = 0; k < D; ++k) acc += h[k] * Whh[g * D + k];
            gate[g] = acc;
        }
        __syncthreads();
        int d = threadIdx.x;
        if (d < D) {
            float ig = sigmoidf_(gate[d]);
            float fg = sigmoidf_(gate[D + d]);
            float gg = tanhf(gate[2 * D + d]);
            float og = sigmoidf_(gate[3 * D + d]);
            float cn = fg * c[d] + ig * gg;
            c[d] = cn;
            float hn = og * tanhf(cn);
            h[d] = hn;
            qh[(b * Q + t) * D + d] = hn;
        }
        __syncthreads();
    }
}

// q2e_vec[l,b,d] = q_last[b,:] . q2e_W[l,d,:] + q2e_b[l,d]
__global__ void k_q2e(const float* __restrict__ qh, const float* __restrict__ q2e_W,
                      const float* __restrict__ q2e_b, float* __restrict__ q2e_vec) {
    __shared__ float row[D];
    int b = blockIdx.x, l = blockIdx.y;
    for (int k = threadIdx.x; k < D; k += blockDim.x) row[k] = qh[(b * Q + (Q - 1)) * D + k];
    __syncthreads();
    int d = threadIdx.x;
    if (d < D) {
        float acc = q2e_b[l * D + d];
        for (int k = 0; k < D; ++k) acc += row[k] * q2e_W[l * D * D + d * D + k];
        q2e_vec[(l * B + b) * D + d] = acc;
    }
}

// Wf[b,f] = sum_q softmax_q(masked s)[q] * s[q],  s[q] = qh[b,q,:].lfe / 10
__global__ void k_wf(const int* __restrict__ kb_rel, const int* __restrict__ qtext,
                     const float* __restrict__ qh, const float* __restrict__ rel_proj,
                     float* __restrict__ Wf) {
    __shared__ float qh_s[Q * D];
    __shared__ float msk[Q];
    int b = blockIdx.y;
    for (int k = threadIdx.x; k < Q * D; k += blockDim.x) qh_s[k] = qh[b * Q * D + k];
    if (threadIdx.x < Q) msk[threadIdx.x] = (qtext[b * Q + threadIdx.x] != NW) ? 1.f : 0.f;
    __syncthreads();
    int f = blockIdx.x * blockDim.x + threadIdx.x;
    if (f >= FC) return;
    int rel = kb_rel[b * FC + f];
    const float* lfe = rel_proj + rel * D;
    float s[Q];
#pragma unroll
    for (int q = 0; q < Q; ++q) s[q] = 0.f;
    for (int k = 0; k < D; ++k) {
        float lv = lfe[k];
#pragma unroll
        for (int q = 0; q < Q; ++q) s[q] += qh_s[q * D + k] * lv;
    }
    float m = -INFINITY;
    float sv[Q];
#pragma unroll
    for (int q = 0; q < Q; ++q) {
        s[q] *= 0.1f;
        sv[q] = s[q] + (1.f - msk[q]) * VERY_NEG;
        m = fmaxf(m, sv[q]);
    }
    float sum = 0.f, wf = 0.f;
    float ex[Q];
#pragma unroll
    for (int q = 0; q < Q; ++q) { ex[q] = expf(sv[q] - m); sum += ex[q]; }
#pragma unroll
    for (int q = 0; q < Q; ++q) wf += (ex[q] / sum) * s[q];
    Wf[b * FC + f] = wf;
}

__global__ void k_wmax(const float* __restrict__ Wf, float* __restrict__ Wmax) {
    __shared__ float red[256];
    int b = blockIdx.x;
    float m = -INFINITY;
    for (int f = threadIdx.x; f < FC; f += 256) m = fmaxf(m, Wf[b * FC + f]);
    red[threadIdx.x] = m;
    __syncthreads();
    for (int s = 128; s > 0; s >>= 1) {
        if (threadIdx.x < s) red[threadIdx.x] = fmaxf(red[threadIdx.x], red[threadIdx.x + s]);
        __syncthreads();
    }
    if (threadIdx.x == 0) Wmax[b] = red[0];
}

__global__ void k_wtilde(const float* __restrict__ Wf, const float* __restrict__ Wmax,
                         const int* __restrict__ e2f, float* __restrict__ W_tilde,
                         float* __restrict__ e2f_sm) {
    int b = blockIdx.y;
    int f = blockIdx.x * 256 + threadIdx.x;
    if (f >= FC) return;
    float wt = expf(Wf[b * FC + f] - Wmax[b]);
    W_tilde[b * FC + f] = wt;
    atomicAdd(&e2f_sm[b * E + e2f[b * FC + f]], wt);
}

// lee[ri,d] = entity_emb[local_entity[ri],:] . ent_W[d,:] + ent_b[d]
__global__ void k_lee_init(const int* __restrict__ local_entity, const float* __restrict__ entity_emb,
                           const float* __restrict__ ent_W, const float* __restrict__ ent_b,
                           float* __restrict__ lee) {
    __shared__ float rows[8][WD];
    __shared__ int ents[8];
    int base = blockIdx.x * 8;
    if (threadIdx.x < 8) ents[threadIdx.x] = local_entity[base + threadIdx.x];
    __syncthreads();
    for (int idx = threadIdx.x; idx < 8 * WD; idx += blockDim.x) {
        int r = idx / WD, k = idx % WD;
        rows[r][k] = entity_emb[ents[r] * WD + k];
    }
    __syncthreads();
    for (int o = threadIdx.x; o < 8 * D; o += blockDim.x) {
        int r = o / D, d = o % D;
        float acc = ent_b[d];
        for (int k = 0; k < WD; ++k) acc += rows[r][k] * ent_W[d * WD + k];
        lee[(base + r) * D + d] = acc;
    }
}

// head[ri,d] and lee_self[ri,d] in one pass over lee rows
__global__ void k_headself(const float* __restrict__ lee, const float* __restrict__ head_W,
                           const float* __restrict__ head_b, const float* __restrict__ self_W,
                           const float* __restrict__ self_b, int l,
                           float* __restrict__ head, float* __restrict__ lee_self) {
    __shared__ float rows[8][D];
    int base = blockIdx.x * 8;
    for (int idx = threadIdx.x; idx < 8 * D; idx += blockDim.x) rows[idx / D][idx % D] = lee[base * D + idx];
    __syncthreads();
    const float* hW = head_W + l * D * D; const float* hb = head_b + l * D;
    const float* sW = self_W + l * D * D; const float* sb = self_b + l * D;
    for (int o = threadIdx.x; o < 2 * 8 * D; o += blockDim.x) {
        int mat = o / (8 * D), rem = o % (8 * D), r = rem / D, d = rem % D;
        const float* W = mat ? sW : hW;
        float acc = mat ? sb[d] : hb[d];
        for (int k = 0; k < D; ++k) acc += rows[r][k] * W[d * D + k];
        (mat ? lee_self : head)[(base + r) * D + d] = acc;
    }
}

// per fact: v = relu(self_proj[rel] + head[e_src]); n = Wt * pr/e2f_sm; scatter n*(v.tailW)+tb
__global__ void k_fact(const int* __restrict__ kb_rel, const int* __restrict__ e2f,
                       const int* __restrict__ f2e, const float* __restrict__ self_proj,
                       const float* __restrict__ head, const float* __restrict__ W_tilde,
                       const float* __restrict__ pr, const float* __restrict__ e2f_sm,
                       const float* __restrict__ tail_W, const float* __restrict__ tail_b, int l,
                       float* __restrict__ f2e_acc, float* __restrict__ pr_acc) {
    __shared__ float v[4][D];
    int wave = threadIdx.x >> 6, lane = threadIdx.x & 63;
    int fid = blockIdx.x * 4 + wave;   // 96000 exact
    int b = fid / FC;
    int rel = kb_rel[fid];
    int es = e2f[fid], ed = f2e[fid];
    const float* sp = self_proj + (l * NREL + rel) * D;
    const float* hrow = head + (b * E + es) * D;
    for (int d = lane; d < D; d += 64) v[wave][d] = fmaxf(0.f, sp[d] + hrow[d]);
    float n = W_tilde[fid] * pr[b * E + es] / fmaxf(e2f_sm[b * E + es], VERY_SMALLF);
    __syncthreads();
    const float* tW = tail_W + l * D * D; const float* tb = tail_b + l * D;
    for (int d = lane; d < D; d += 64) {
        float acc = 0.f;
        for (int k = 0; k < D; ++k) acc += v[wave][k] * tW[d * D + k];
        atomicAdd(&f2e_acc[(b * E + ed) * D + d], n * acc + tb[d]);
    }
    if (lane == 0) atomicAdd(&pr_acc[b * E + ed], n);
}

// entity update: nxt=[lee, q2e_vec, 3*relu(lee_self+f2e_acc)] ; lee_out = relu(nxt @ e2e_W.T + b)
__global__ void k_entity(const float* __restrict__ lee, const float* __restrict__ lee_self,
                         const float* __restrict__ f2e_acc, const float* __restrict__ q2e_vec,
                         const float* __restrict__ e2e_W, const float* __restrict__ e2e_b, int l,
                         const float* __restrict__ pr_acc, float* __restrict__ pr,
                         float* __restrict__ lee_out) {
    __shared__ float nxt[8][3 * D];
    int base = blockIdx.x * 8;
    for (int idx = threadIdx.x; idx < 8 * 3 * D; idx += blockDim.x) {
        int r = idx / (3 * D), k = idx % (3 * D);
        int ri = base + r; int b = ri / E;
        float val;
        if (k < D) val = lee[ri * D + k];
        else if (k < 2 * D) val = q2e_vec[(l * B + b) * D + (k - D)];
        else { int j = k - 2 * D; val = 3.0f * fmaxf(0.f, lee_self[ri * D + j] + f2e_acc[ri * D + j]); }
        nxt[r][k] = val;
    }
    __syncthreads();
    const float* W = e2e_W + l * D * 3 * D; const float* bb = e2e_b + l * D;
    for (int o = threadIdx.x; o < 8 * D; o += blockDim.x) {
        int r = o / D, d = o % D;
        float acc = bb[d];
        for (int k = 0; k < 3 * D; ++k) acc += nxt[r][k] * W[d * 3 * D + k];
        lee_out[(base + r) * D + d] = fmaxf(0.f, acc);
    }
    if (threadIdx.x < 8) {
        int ri = base + threadIdx.x;
        pr[ri] = 0.8f * pr_acc[ri] + 0.2f * pr[ri];
    }
}

__global__ void k_score(const int* __restrict__ local_entity, const float* __restrict__ lee,
                        const float* __restrict__ score_W, const float* __restrict__ score_b,
                        float* __restrict__ out) {
    int i = blockIdx.x * 256 + threadIdx.x;
    if (i >= B * E) return;
    if (local_entity[i] == NE) { out[i] = 0.f; return; }
    float acc = score_b[0];
    for (int k = 0; k < D; ++k) acc += lee[i * D + k] * score_W[k];
    out[i] = 1.f / (1.f + expf(-acc));
}

extern "C" void kernel_launch(void* const* d_in, const int* in_sizes, int n_in,
                              void* d_out, int out_size, void* d_ws, size_t ws_size,
                              hipStream_t stream) {
    const int*   local_entity = (const int*)d_in[0];
    const float* q2e_adj      = (const float*)d_in[1];
    const int*   kb_rel       = (const int*)d_in[2];
    const int*   qtext        = (const int*)d_in[3];
    const int*   e2f          = (const int*)d_in[4];
    const int*   f2e          = (const int*)d_in[5];
    const float* word_emb     = (const float*)d_in[7];
    const float* entity_emb   = (const float*)d_in[8];
    const float* rel_emb      = (const float*)d_in[9];
    const float* ent_W        = (const float*)d_in[10];
    const float* ent_b        = (const float*)d_in[11];
    const float* rel_W        = (const float*)d_in[12];
    const float* rel_b        = (const float*)d_in[13];
    const float* lstm_Wih     = (const float*)d_in[14];
    const float* lstm_Whh     = (const float*)d_in[15];
    const float* lstm_bih     = (const float*)d_in[16];
    const float* lstm_bhh     = (const float*)d_in[17];
    const float* q2e_W        = (const float*)d_in[18];
    const float* q2e_b        = (const float*)d_in[19];
    const float* head_W       = (const float*)d_in[20];
    const float* head_b       = (const float*)d_in[21];
    const float* tail_W       = (const float*)d_in[22];
    const float* tail_b       = (const float*)d_in[23];
    const float* self_W       = (const float*)d_in[24];
    const float* self_b       = (const float*)d_in[25];
    const float* e2e_W        = (const float*)d_in[26];
    const float* e2e_b        = (const float*)d_in[27];
    const float* score_W      = (const float*)d_in[28];
    const float* score_b      = (const float*)d_in[29];

    float* ws = (float*)d_ws;
    float* rel_proj  = ws;                      // 30100
    float* self_proj = rel_proj  + NREL * D;    // 90300
    float* xW        = self_proj + 3 * NREL * D;// 64000
    float* qh        = xW        + B * Q * G4;  // 16000
    float* q2e_vec   = qh        + B * Q * D;   // 2400
    float* Wf        = q2e_vec   + 3 * B * D;   // 96000
    float* Wmax      = Wf        + B * FC;      // 8
    float* W_tilde   = Wmax      + 8;           // 96000
    float* e2f_sm    = W_tilde   + B * FC;      // 16000
    float* leeA      = e2f_sm    + B * E;       // 1600000
    float* leeB      = leeA      + B * E * D;
    float* head      = leeB      + B * E * D;
    float* lee_self  = head      + B * E * D;
    float* f2e_acc   = lee_self  + B * E * D;
    float* pr        = f2e_acc   + B * E * D;   // 16000
    float* pr_acc    = pr        + B * E;       // 16000

    hipMemcpyAsync(pr, q2e_adj, (size_t)B * E * sizeof(float), hipMemcpyDeviceToDevice, stream);

    k_rel_proj<<<NREL, 128, 0, stream>>>(rel_emb, rel_W, rel_b, rel_proj);
    k_self_proj<<<dim3(NREL, 3), 128, 0, stream>>>(rel_proj, self_W, self_b, self_proj);
    k_xw<<<B * Q, 256, 0, stream>>>(qtext, word_emb, lstm_Wih, lstm_bih, lstm_bhh, xW);
    k_lstm<<<B, 512, 0, stream>>>(xW, lstm_Whh, qh);
    k_q2e<<<dim3(B, 3), 128, 0, stream>>>(qh, q2e_W, q2e_b, q2e_vec);
    k_wf<<<dim3((FC + 255) / 256, B), 256, 0, stream>>>(kb_rel, qtext, qh, rel_proj, Wf);
    k_wmax<<<B, 256, 0, stream>>>(Wf, Wmax);
    hipMemsetAsync(e2f_sm, 0, (size_t)B * E * sizeof(float), stream);
    k_wtilde<<<dim3((FC + 255) / 256, B), 256, 0, stream>>>(Wf, Wmax, e2f, W_tilde, e2f_sm);
    k_lee_init<<<(B * E) / 8, 256, 0, stream>>>(local_entity, entity_emb, ent_W, ent_b, leeA);

    float* cur = leeA; float* nxt = leeB;
    for (int l = 0; l < 3; ++l) {
        k_headself<<<(B * E) / 8, 256, 0, stream>>>(cur, head_W, head_b, self_W, self_b, l, head, lee_self);
        hipMemsetAsync(f2e_acc, 0, (size_t)B * E * D * sizeof(float), stream);
        hipMemsetAsync(pr_acc, 0, (size_t)B * E * sizeof(float), stream);
        k_fact<<<(B * FC) / 4, 256, 0, stream>>>(kb_rel, e2f, f2e, self_proj, head, W_tilde, pr,
                                                 e2f_sm, tail_W, tail_b, l, f2e_acc, pr_acc);
        k_entity<<<(B * E) / 8, 256, 0, stream>>>(cur, lee_self, f2e_acc, q2e_vec, e2e_W, e2e_b, l,
                                                  pr_acc, pr, nxt);
        float* tmp = cur; cur = nxt; nxt = tmp;
    }
    k_score<<<(B * E + 255) / 256, 256, 0, stream>>>(local_entity, cur, score_W, score_b, (float*)d_out);
}

// Round 2
// 1422.398 us; speedup vs baseline: 1.3968x; 1.3968x over previous
//
#include <hip/hip_runtime.h>
#include <math.h>

#define VERY_NEG  -100000000000.0f
#define VERY_SMALLF 1e-10f

constexpr int B  = 8;
constexpr int E  = 2000;
constexpr int FC = 12000;
constexpr int Q  = 20;
constexpr int WD = 300;
constexpr int D  = 100;
constexpr int NW = 40000;
constexpr int NE = 100000;
constexpr int G4 = 4 * D;   // 400
constexpr int NREL = 301;
constexpr int NF = B * FC;  // 96000
constexpr int NR_ = B * E;  // 16000 destination rows

__device__ __forceinline__ float sigmoidf_(float x) { return 1.0f / (1.0f + expf(-x)); }

// ---------------- one-time prep ----------------

__global__ void k_rel_proj(const float* __restrict__ rel_emb, const float* __restrict__ rel_W,
                           const float* __restrict__ rel_b, float* __restrict__ rel_proj) {
    __shared__ float row[2 * WD];
    int r = blockIdx.x;
    for (int k = threadIdx.x; k < 2 * WD; k += blockDim.x) row[k] = rel_emb[r * 2 * WD + k];
    __syncthreads();
    int d = threadIdx.x;
    if (d < D) {
        float acc = rel_b[d];
        for (int k = 0; k < 2 * WD; ++k) acc += row[k] * rel_W[d * 2 * WD + k];
        rel_proj[r * D + d] = acc;
    }
}

__global__ void k_self_proj(const float* __restrict__ rel_proj, const float* __restrict__ self_W,
                            const float* __restrict__ self_b, float* __restrict__ self_proj) {
    __shared__ float row[D];
    int r = blockIdx.x, l = blockIdx.y;
    for (int k = threadIdx.x; k < D; k += blockDim.x) row[k] = rel_proj[r * D + k];
    __syncthreads();
    int d = threadIdx.x;
    if (d < D) {
        float acc = self_b[l * D + d];
        for (int k = 0; k < D; ++k) acc += row[k] * self_W[l * D * D + d * D + k];
        self_proj[(l * NREL + r) * D + d] = acc;
    }
}

__global__ void k_xw(const int* __restrict__ qtext, const float* __restrict__ word_emb,
                     const float* __restrict__ Wih, const float* __restrict__ bih,
                     const float* __restrict__ bhh, float* __restrict__ xW) {
    __shared__ float row[WD];
    int bt = blockIdx.x;
    int w = qtext[bt];
    for (int k = threadIdx.x; k < WD; k += blockDim.x) row[k] = word_emb[w * WD + k];
    __syncthreads();
    for (int g = threadIdx.x; g < G4; g += blockDim.x) {
        float acc = bih[g] + bhh[g];
        for (int k = 0; k < WD; ++k) acc += row[k] * Wih[g * WD + k];
        xW[bt * G4 + g] = acc;
    }
}

__global__ void k_lstm(const float* __restrict__ xW, const float* __restrict__ Whh,
                       float* __restrict__ qh) {
    __shared__ float h[D], c[D], gate[G4];
    int b = blockIdx.x;
    if (threadIdx.x < D) { h[threadIdx.x] = 0.f; c[threadIdx.x] = 0.f; }
    __syncthreads();
    for (int t = 0; t < Q; ++t) {
        int g = threadIdx.x;
        if (g < G4) {
            float acc = xW[(b * Q + t) * G4 + g];
            for (int k = 0; k < D; ++k) acc += h[k] * Whh[g * D + k];
            gate[g] = acc;
        }
        __syncthreads();
        int d = threadIdx.x;
        if (d < D) {
            float ig = sigmoidf_(gate[d]);
            float fg = sigmoidf_(gate[D + d]);
            float gg = tanhf(gate[2 * D + d]);
            float og = sigmoidf_(gate[3 * D + d]);
            float cn = fg * c[d] + ig * gg;
            c[d] = cn;
            float hn = og * tanhf(cn);
            h[d] = hn;
            qh[(b * Q + t) * D + d] = hn;
        }
        __syncthreads();
    }
}

__global__ void k_q2e(const float* __restrict__ qh, const float* __restrict__ q2e_W,
                      const float* __restrict__ q2e_b, float* __restrict__ q2e_vec) {
    __shared__ float row[D];
    int b = blockIdx.x, l = blockIdx.y;
    for (int k = threadIdx.x; k < D; k += blockDim.x) row[k] = qh[(b * Q + (Q - 1)) * D + k];
    __syncthreads();
    int d = threadIdx.x;
    if (d < D) {
        float acc = q2e_b[l * D + d];
        for (int k = 0; k < D; ++k) acc += row[k] * q2e_W[l * D * D + d * D + k];
        q2e_vec[(l * B + b) * D + d] = acc;
    }
}

__global__ void k_wf(const int* __restrict__ kb_rel, const int* __restrict__ qtext,
                     const float* __restrict__ qh, const float* __restrict__ rel_proj,
                     float* __restrict__ Wf) {
    __shared__ float qh_s[Q * D];
    __shared__ float msk[Q];
    int b = blockIdx.y;
    for (int k = threadIdx.x; k < Q * D; k += blockDim.x) qh_s[k] = qh[b * Q * D + k];
    if (threadIdx.x < Q) msk[threadIdx.x] = (qtext[b * Q + threadIdx.x] != NW) ? 1.f : 0.f;
    __syncthreads();
    int f = blockIdx.x * blockDim.x + threadIdx.x;
    if (f >= FC) return;
    int rel = kb_rel[b * FC + f];
    const float* lfe = rel_proj + rel * D;
    float s[Q];
#pragma unroll
    for (int q = 0; q < Q; ++q) s[q] = 0.f;
    for (int k = 0; k < D; ++k) {
        float lv = lfe[k];
#pragma unroll
        for (int q = 0; q < Q; ++q) s[q] += qh_s[q * D + k] * lv;
    }
    float m = -INFINITY;
    float sv[Q];
#pragma unroll
    for (int q = 0; q < Q; ++q) {
        s[q] *= 0.1f;
        sv[q] = s[q] + (1.f - msk[q]) * VERY_NEG;
        m = fmaxf(m, sv[q]);
    }
    float sum = 0.f, wf = 0.f;
    float ex[Q];
#pragma unroll
    for (int q = 0; q < Q; ++q) { ex[q] = expf(sv[q] - m); sum += ex[q]; }
#pragma unroll
    for (int q = 0; q < Q; ++q) wf += (ex[q] / sum) * s[q];
    Wf[b * FC + f] = wf;
}

__global__ void k_wmax(const float* __restrict__ Wf, float* __restrict__ Wmax) {
    __shared__ float red[256];
    int b = blockIdx.x;
    float m = -INFINITY;
    for (int f = threadIdx.x; f < FC; f += 256) m = fmaxf(m, Wf[b * FC + f]);
    red[threadIdx.x] = m;
    __syncthreads();
    for (int s = 128; s > 0; s >>= 1) {
        if (threadIdx.x < s) red[threadIdx.x] = fmaxf(red[threadIdx.x], red[threadIdx.x + s]);
        __syncthreads();
    }
    if (threadIdx.x == 0) Wmax[b] = red[0];
}

__global__ void k_wtilde(const float* __restrict__ Wf, const float* __restrict__ Wmax,
                         const int* __restrict__ e2f, float* __restrict__ W_tilde,
                         float* __restrict__ e2f_sm) {
    int b = blockIdx.y;
    int f = blockIdx.x * 256 + threadIdx.x;
    if (f >= FC) return;
    float wt = expf(Wf[b * FC + f] - Wmax[b]);
    W_tilde[b * FC + f] = wt;
    atomicAdd(&e2f_sm[b * E + e2f[b * FC + f]], wt);
}

__global__ void k_lee_init(const int* __restrict__ local_entity, const float* __restrict__ entity_emb,
                           const float* __restrict__ ent_W, const float* __restrict__ ent_b,
                           float* __restrict__ lee) {
    __shared__ float rows[8][WD];
    __shared__ int ents[8];
    int base = blockIdx.x * 8;
    if (threadIdx.x < 8) ents[threadIdx.x] = local_entity[base + threadIdx.x];
    __syncthreads();
    for (int idx = threadIdx.x; idx < 8 * WD; idx += blockDim.x) {
        int r = idx / WD, k = idx % WD;
        rows[r][k] = entity_emb[ents[r] * WD + k];
    }
    __syncthreads();
    for (int o = threadIdx.x; o < 8 * D; o += blockDim.x) {
        int r = o / D, d = o % D;
        float acc = ent_b[d];
        for (int k = 0; k < WD; ++k) acc += rows[r][k] * ent_W[d * WD + k];
        lee[(base + r) * D + d] = acc;
    }
}

// ---------------- counting sort of facts by destination (b, f2e) — layer-invariant ----------------

__global__ void k_hist(const int* __restrict__ f2e, int* __restrict__ cnt) {
    int fid = blockIdx.x * 256 + threadIdx.x;
    if (fid >= NF) return;
    int ri = (fid / FC) * E + f2e[fid];
    atomicAdd(&cnt[ri], 1);
}

// single-block exclusive scan of cnt[NR_] -> off[NR_+1], cursor copy
__global__ void k_scan(const int* __restrict__ cnt, int* __restrict__ off, int* __restrict__ cursor) {
    __shared__ int part[256];
    constexpr int CH = (NR_ + 255) / 256;  // 63
    int t = threadIdx.x;
    int base = t * CH;
    int s = 0;
    for (int i = 0; i < CH; ++i) {
        int idx = base + i;
        if (idx < NR_) s += cnt[idx];
    }
    part[t] = s;
    __syncthreads();
    for (int d = 1; d < 256; d <<= 1) {
        int add = (t >= d) ? part[t - d] : 0;
        __syncthreads();
        part[t] += add;
        __syncthreads();
    }
    int run = part[t] - s;  // exclusive prefix
    for (int i = 0; i < CH; ++i) {
        int idx = base + i;
        if (idx < NR_) {
            off[idx] = run;
            cursor[idx] = run;
            run += cnt[idx];
        }
    }
    if (t == 255) off[NR_] = part[255];
}

__global__ void k_scatter(const int* __restrict__ f2e, int* __restrict__ cursor,
                          int* __restrict__ sorted_fid) {
    int fid = blockIdx.x * 256 + threadIdx.x;
    if (fid >= NF) return;
    int ri = (fid / FC) * E + f2e[fid];
    int pos = atomicAdd(&cursor[ri], 1);
    sorted_fid[pos] = fid;
}

// ---------------- per-layer kernels ----------------

__global__ void k_headself(const float* __restrict__ lee, const float* __restrict__ head_W,
                           const float* __restrict__ head_b, const float* __restrict__ self_W,
                           const float* __restrict__ self_b, int l,
                           float* __restrict__ head, float* __restrict__ lee_self) {
    __shared__ float rows[8][D];
    int base = blockIdx.x * 8;
    for (int idx = threadIdx.x; idx < 8 * D; idx += blockDim.x) rows[idx / D][idx % D] = lee[base * D + idx];
    __syncthreads();
    const float* hW = head_W + l * D * D; const float* hb = head_b + l * D;
    const float* sW = self_W + l * D * D; const float* sb = self_b + l * D;
    for (int o = threadIdx.x; o < 2 * 8 * D; o += blockDim.x) {
        int mat = o / (8 * D), rem = o % (8 * D), r = rem / D, d = rem % D;
        const float* W = mat ? sW : hW;
        float acc = mat ? sb[d] : hb[d];
        for (int k = 0; k < D; ++k) acc += rows[r][k] * W[d * D + k];
        (mat ? lee_self : head)[(base + r) * D + d] = acc;
    }
}

__global__ void k_n(const float* __restrict__ W_tilde, const float* __restrict__ pr,
                    const float* __restrict__ e2f_sm, const int* __restrict__ e2f,
                    float* __restrict__ n) {
    int fid = blockIdx.x * 256 + threadIdx.x;
    if (fid >= NF) return;
    int b = fid / FC;
    int es = e2f[fid];
    n[fid] = W_tilde[fid] * pr[b * E + es] / fmaxf(e2f_sm[b * E + es], VERY_SMALLF);
}

// one wave per destination row: u[ri,:] = sum_f n_f * relu(self_proj[rel_f] + head[es_f]); pr_acc = sum n_f
__global__ void k_gather(const int* __restrict__ sorted_fid, const int* __restrict__ off,
                         const float* __restrict__ n, const int* __restrict__ kb_rel,
                         const int* __restrict__ e2f, const float* __restrict__ self_proj,
                         const float* __restrict__ head, int l,
                         float* __restrict__ u, float* __restrict__ pr_acc) {
    int wave = threadIdx.x >> 6, lane = threadIdx.x & 63;
    int ri = blockIdx.x * 4 + wave;   // NR_ exact
    int b = ri / E;
    int s = off[ri], e = off[ri + 1];
    float a0 = 0.f, a1 = 0.f, ns = 0.f;
    const float* spb = self_proj + l * NREL * D;
    const float* hb = head + b * E * D;
    for (int j = s; j < e; ++j) {
        int fid = sorted_fid[j];
        float nj = n[fid];
        int rel = kb_rel[fid];
        int es = e2f[fid];
        const float* sp = spb + rel * D;
        const float* hr = hb + es * D;
        a0 += nj * fmaxf(0.f, sp[lane] + hr[lane]);
        if (lane < D - 64) a1 += nj * fmaxf(0.f, sp[lane + 64] + hr[lane + 64]);
        ns += nj;
    }
    u[ri * D + lane] = a0;
    if (lane < D - 64) u[ri * D + 64 + lane] = a1;
    if (lane == 0) pr_acc[ri] = ns;
}

// f2e_acc[ri,:] = tail_W @ u[ri,:] + cnt(ri) * tail_b
__global__ void k_tail(const float* __restrict__ u, const int* __restrict__ off,
                       const float* __restrict__ tail_W, const float* __restrict__ tail_b, int l,
                       float* __restrict__ f2e_acc) {
    __shared__ float rows[8][D];
    __shared__ float cs[8];
    int base = blockIdx.x * 8;
    for (int idx = threadIdx.x; idx < 8 * D; idx += blockDim.x) rows[idx / D][idx % D] = u[base * D + idx];
    if (threadIdx.x < 8) {
        int ri = base + threadIdx.x;
        cs[threadIdx.x] = (float)(off[ri + 1] - off[ri]);
    }
    __syncthreads();
    const float* tW = tail_W + l * D * D; const float* tb = tail_b + l * D;
    for (int o = threadIdx.x; o < 8 * D; o += blockDim.x) {
        int r = o / D, d = o % D;
        float acc = cs[r] * tb[d];
        for (int k = 0; k < D; ++k) acc += rows[r][k] * tW[d * D + k];
        f2e_acc[(base + r) * D + d] = acc;
    }
}

__global__ void k_entity(const float* __restrict__ lee, const float* __restrict__ lee_self,
                         const float* __restrict__ f2e_acc, const float* __restrict__ q2e_vec,
                         const float* __restrict__ e2e_W, const float* __restrict__ e2e_b, int l,
                         const float* __restrict__ pr_acc, float* __restrict__ pr,
                         float* __restrict__ lee_out) {
    __shared__ float nxt[8][3 * D];
    int base = blockIdx.x * 8;
    for (int idx = threadIdx.x; idx < 8 * 3 * D; idx += blockDim.x) {
        int r = idx / (3 * D), k = idx % (3 * D);
        int ri = base + r; int b = ri / E;
        float val;
        if (k < D) val = lee[ri * D + k];
        else if (k < 2 * D) val = q2e_vec[(l * B + b) * D + (k - D)];
        else { int j = k - 2 * D; val = 3.0f * fmaxf(0.f, lee_self[ri * D + j] + f2e_acc[ri * D + j]); }
        nxt[r][k] = val;
    }
    __syncthreads();
    const float* W = e2e_W + l * D * 3 * D; const float* bb = e2e_b + l * D;
    for (int o = threadIdx.x; o < 8 * D; o += blockDim.x) {
        int r = o / D, d = o % D;
        float acc = bb[d];
        for (int k = 0; k < 3 * D; ++k) acc += nxt[r][k] * W[d * 3 * D + k];
        lee_out[(base + r) * D + d] = fmaxf(0.f, acc);
    }
    if (threadIdx.x < 8) {
        int ri = base + threadIdx.x;
        pr[ri] = 0.8f * pr_acc[ri] + 0.2f * pr[ri];
    }
}

__global__ void k_score(const int* __restrict__ local_entity, const float* __restrict__ lee,
                        const float* __restrict__ score_W, const float* __restrict__ score_b,
                        float* __restrict__ out) {
    int i = blockIdx.x * 256 + threadIdx.x;
    if (i >= B * E) return;
    if (local_entity[i] == NE) { out[i] = 0.f; return; }
    float acc = score_b[0];
    for (int k = 0; k < D; ++k) acc += lee[i * D + k] * score_W[k];
    out[i] = 1.f / (1.f + expf(-acc));
}

extern "C" void kernel_launch(void* const* d_in, const int* in_sizes, int n_in,
                              void* d_out, int out_size, void* d_ws, size_t ws_size,
                              hipStream_t stream) {
    const int*   local_entity = (const int*)d_in[0];
    const float* q2e_adj      = (const float*)d_in[1];
    const int*   kb_rel       = (const int*)d_in[2];
    const int*   qtext        = (const int*)d_in[3];
    const int*   e2f          = (const int*)d_in[4];
    const int*   f2e          = (const int*)d_in[5];
    const float* word_emb     = (const float*)d_in[7];
    const float* entity_emb   = (const float*)d_in[8];
    const float* rel_emb      = (const float*)d_in[9];
    const float* ent_W        = (const float*)d_in[10];
    const float* ent_b        = (const float*)d_in[11];
    const float* rel_W        = (const float*)d_in[12];
    const float* rel_b        = (const float*)d_in[13];
    const float* lstm_Wih     = (const float*)d_in[14];
    const float* lstm_Whh     = (const float*)d_in[15];
    const float* lstm_bih     = (const float*)d_in[16];
    const float* lstm_bhh     = (const float*)d_in[17];
    const float* q2e_W        = (const float*)d_in[18];
    const float* q2e_b        = (const float*)d_in[19];
    const float* head_W       = (const float*)d_in[20];
    const float* head_b       = (const float*)d_in[21];
    const float* tail_W       = (const float*)d_in[22];
    const float* tail_b       = (const float*)d_in[23];
    const float* self_W       = (const float*)d_in[24];
    const float* self_b       = (const float*)d_in[25];
    const float* e2e_W        = (const float*)d_in[26];
    const float* e2e_b        = (const float*)d_in[27];
    const float* score_W      = (const float*)d_in[28];
    const float* score_b      = (const float*)d_in[29];

    float* ws = (float*)d_ws;
    float* rel_proj  = ws;                      // 30100
    float* self_proj = rel_proj  + NREL * D;    // 90300
    float* xW        = self_proj + 3 * NREL * D;// 64000
    float* qh        = xW        + B * Q * G4;  // 16000
    float* q2e_vec   = qh        + B * Q * D;   // 2400
    float* Wf        = q2e_vec   + 3 * B * D;   // 96000
    float* Wmax      = Wf        + B * FC;      // 8
    float* W_tilde   = Wmax      + 8;           // 96000
    float* e2f_sm    = W_tilde   + B * FC;      // 16000
    float* leeA      = e2f_sm    + B * E;       // 1.6M
    float* leeB      = leeA      + B * E * D;
    float* head      = leeB      + B * E * D;
    float* lee_self  = head      + B * E * D;
    float* f2e_acc   = lee_self  + B * E * D;
    float* pr        = f2e_acc   + B * E * D;   // 16000
    float* pr_acc    = pr        + B * E;       // 16000
    float* n_buf     = pr_acc    + B * E;       // 96000
    float* u_buf     = n_buf     + NF;          // 1.6M
    int*   cnt       = (int*)(u_buf + B * E * D);   // 16000
    int*   cursor    = cnt       + NR_;         // 16000
    int*   off       = cursor    + NR_;         // 16001
    int*   sorted    = off       + NR_ + 1;     // 96000

    hipMemcpyAsync(pr, q2e_adj, (size_t)B * E * sizeof(float), hipMemcpyDeviceToDevice, stream);
    hipMemsetAsync(cnt, 0, NR_ * sizeof(int), stream);
    hipMemsetAsync(e2f_sm, 0, (size_t)B * E * sizeof(float), stream);

    // layer-invariant counting sort of facts by (b, f2e)
    k_hist<<<(NF + 255) / 256, 256, 0, stream>>>(f2e, cnt);
    k_scan<<<1, 256, 0, stream>>>(cnt, off, cursor);
    k_scatter<<<(NF + 255) / 256, 256, 0, stream>>>(f2e, cursor, sorted);

    k_rel_proj<<<NREL, 128, 0, stream>>>(rel_emb, rel_W, rel_b, rel_proj);
    k_self_proj<<<dim3(NREL, 3), 128, 0, stream>>>(rel_proj, self_W, self_b, self_proj);
    k_xw<<<B * Q, 256, 0, stream>>>(qtext, word_emb, lstm_Wih, lstm_bih, lstm_bhh, xW);
    k_lstm<<<B, 512, 0, stream>>>(xW, lstm_Whh, qh);
    k_q2e<<<dim3(B, 3), 128, 0, stream>>>(qh, q2e_W, q2e_b, q2e_vec);
    k_wf<<<dim3((FC + 255) / 256, B), 256, 0, stream>>>(kb_rel, qtext, qh, rel_proj, Wf);
    k_wmax<<<B, 256, 0, stream>>>(Wf, Wmax);
    k_wtilde<<<dim3((FC + 255) / 256, B), 256, 0, stream>>>(Wf, Wmax, e2f, W_tilde, e2f_sm);
    k_lee_init<<<(B * E) / 8, 256, 0, stream>>>(local_entity, entity_emb, ent_W, ent_b, leeA);

    float* cur = leeA; float* nxt = leeB;
    for (int l = 0; l < 3; ++l) {
        k_headself<<<(B * E) / 8, 256, 0, stream>>>(cur, head_W, head_b, self_W, self_b, l, head, lee_self);
        k_n<<<(NF + 255) / 256, 256, 0, stream>>>(W_tilde, pr, e2f_sm, e2f, n_buf);
        k_gather<<<NR_ / 4, 256, 0, stream>>>(sorted, off, n_buf, kb_rel, e2f, self_proj, head, l,
                                              u_buf, pr_acc);
        k_tail<<<NR_ / 8, 256, 0, stream>>>(u_buf, off, tail_W, tail_b, l, f2e_acc);
        k_entity<<<NR_ / 8, 256, 0, stream>>>(cur, lee_self, f2e_acc, q2e_vec, e2e_W, e2e_b, l,
                                              pr_acc, pr, nxt);
        float* tmp = cur; cur = nxt; nxt = tmp;
    }
    k_score<<<(B * E + 255) / 256, 256, 0, stream>>>(local_entity, cur, score_W, score_b, (float*)d_out);
}

// Round 3
// 717.272 us; speedup vs baseline: 2.7699x; 1.9831x over previous
//
#include <hip/hip_runtime.h>
#include <math.h>

#define VERY_NEG  -100000000000.0f
#define VERY_SMALLF 1e-10f

constexpr int B  = 8;
constexpr int E  = 2000;
constexpr int FC = 12000;
constexpr int Q  = 20;
constexpr int WD = 300;
constexpr int D  = 100;
constexpr int NW = 40000;
constexpr int NE = 100000;
constexpr int G4 = 4 * D;   // 400
constexpr int NREL = 301;
constexpr int NF = B * FC;  // 96000
constexpr int NR_ = B * E;  // 16000 rows

__device__ __forceinline__ float sigmoidf_(float x) { return 1.0f / (1.0f + expf(-x)); }

// ================= generic register-tiled GEMM: C[16000][100] = act(A @ W^T + rs*b) =================
// block: 256 thr = 8 row-groups(4 rows) x 32 col-groups(4 cols); BR=32 rows/block; K chunked by 50.
constexpr int BR = 32;
constexpr int KC = 50;
constexpr int DP = 128;

template<int K, int ACT>
__global__ __launch_bounds__(256) void k_gemm(const float* __restrict__ A, const float* __restrict__ W,
                                              const float* __restrict__ bias,
                                              const float* __restrict__ row_scale,
                                              const int* __restrict__ row_idx,
                                              float* __restrict__ C) {
    __shared__ float As[KC][BR];
    __shared__ float Bs[KC][DP];
    __shared__ int rix[BR];
    int tid = threadIdx.x;
    int base = blockIdx.x * BR;
    if (tid < BR) rix[tid] = row_idx ? row_idx[base + tid] : (base + tid);
    int cg = tid & 31, rg = tid >> 5;
    float bv[4];
#pragma unroll
    for (int j = 0; j < 4; ++j) { int c = 4 * cg + j; bv[j] = (c < D) ? bias[c] : 0.f; }
    float acc[4][4];
#pragma unroll
    for (int i = 0; i < 4; ++i)
#pragma unroll
        for (int j = 0; j < 4; ++j) acc[i][j] = 0.f;
    for (int k0 = 0; k0 < K; k0 += KC) {
        __syncthreads();
        for (int i = tid; i < KC * BR; i += 256) {
            int k = i >> 5, r = i & 31;
            As[k][r] = A[(size_t)rix[r] * K + k0 + k];
        }
        for (int i = tid; i < KC * DP; i += 256) {
            int k = i >> 7, d = i & 127;
            Bs[k][d] = (d < D) ? W[d * K + k0 + k] : 0.f;
        }
        __syncthreads();
#pragma unroll 10
        for (int k = 0; k < KC; ++k) {
            float4 a4 = *(const float4*)&As[k][rg * 4];
            float4 b4 = *(const float4*)&Bs[k][cg * 4];
            float a[4] = {a4.x, a4.y, a4.z, a4.w};
            float bb[4] = {b4.x, b4.y, b4.z, b4.w};
#pragma unroll
            for (int i = 0; i < 4; ++i)
#pragma unroll
                for (int j = 0; j < 4; ++j) acc[i][j] += a[i] * bb[j];
        }
    }
    if (cg < 25) {
#pragma unroll
        for (int i = 0; i < 4; ++i) {
            int r = base + rg * 4 + i;
            float sc = row_scale ? row_scale[r] : 1.f;
            float4 o;
            float v0 = acc[i][0] + sc * bv[0]; float v1 = acc[i][1] + sc * bv[1];
            float v2 = acc[i][2] + sc * bv[2]; float v3 = acc[i][3] + sc * bv[3];
            if (ACT) { v0 = fmaxf(v0, 0.f); v1 = fmaxf(v1, 0.f); v2 = fmaxf(v2, 0.f); v3 = fmaxf(v3, 0.f); }
            o.x = v0; o.y = v1; o.z = v2; o.w = v3;
            *(float4*)&C[(size_t)r * D + 4 * cg] = o;
        }
    }
}

// entity-update GEMM: A = concat(lee, q2e_bcast, 3*relu(lee_self+f2e_acc)) K=300; relu out; + pr update
__global__ __launch_bounds__(256) void k_gemm_ent(const float* __restrict__ lee,
                                                  const float* __restrict__ lee_self,
                                                  const float* __restrict__ f2e_acc,
                                                  const float* __restrict__ q2e,   // + l*B*D
                                                  const float* __restrict__ W,     // + l*D*3D
                                                  const float* __restrict__ bias,  // + l*D
                                                  const float* __restrict__ pr_acc,
                                                  float* __restrict__ pr,
                                                  float* __restrict__ C) {
    __shared__ float As[KC][BR];
    __shared__ float Bs[KC][DP];
    int tid = threadIdx.x;
    int base = blockIdx.x * BR;
    int cg = tid & 31, rg = tid >> 5;
    float bv[4];
#pragma unroll
    for (int j = 0; j < 4; ++j) { int c = 4 * cg + j; bv[j] = (c < D) ? bias[c] : 0.f; }
    float acc[4][4];
#pragma unroll
    for (int i = 0; i < 4; ++i)
#pragma unroll
        for (int j = 0; j < 4; ++j) acc[i][j] = 0.f;
    for (int k0 = 0; k0 < 3 * D; k0 += KC) {
        __syncthreads();
        for (int i = tid; i < KC * BR; i += 256) {
            int k = i >> 5, r = i & 31;
            int ri = base + r;
            int gk = k0 + k;
            float v;
            if (gk < D) v = lee[ri * D + gk];
            else if (gk < 2 * D) v = q2e[(ri / E) * D + (gk - D)];
            else { int j = gk - 2 * D; v = 3.0f * fmaxf(0.f, lee_self[ri * D + j] + f2e_acc[ri * D + j]); }
            As[k][r] = v;
        }
        for (int i = tid; i < KC * DP; i += 256) {
            int k = i >> 7, d = i & 127;
            Bs[k][d] = (d < D) ? W[d * 3 * D + k0 + k] : 0.f;
        }
        __syncthreads();
#pragma unroll 10
        for (int k = 0; k < KC; ++k) {
            float4 a4 = *(const float4*)&As[k][rg * 4];
            float4 b4 = *(const float4*)&Bs[k][cg * 4];
            float a[4] = {a4.x, a4.y, a4.z, a4.w};
            float bb[4] = {b4.x, b4.y, b4.z, b4.w};
#pragma unroll
            for (int i = 0; i < 4; ++i)
#pragma unroll
                for (int j = 0; j < 4; ++j) acc[i][j] += a[i] * bb[j];
        }
    }
    if (cg < 25) {
#pragma unroll
        for (int i = 0; i < 4; ++i) {
            int r = base + rg * 4 + i;
            float4 o;
            o.x = fmaxf(acc[i][0] + bv[0], 0.f); o.y = fmaxf(acc[i][1] + bv[1], 0.f);
            o.z = fmaxf(acc[i][2] + bv[2], 0.f); o.w = fmaxf(acc[i][3] + bv[3], 0.f);
            *(float4*)&C[(size_t)r * D + 4 * cg] = o;
        }
    }
    if (tid < BR) {
        int ri = base + tid;
        pr[ri] = 0.8f * pr_acc[ri] + 0.2f * pr[ri];
    }
}

// ================= small prep kernels =================

__global__ void k_rel_proj(const float* __restrict__ rel_emb, const float* __restrict__ rel_W,
                           const float* __restrict__ rel_b, float* __restrict__ rel_proj) {
    __shared__ float row[2 * WD];
    int r = blockIdx.x;
    for (int k = threadIdx.x; k < 2 * WD; k += blockDim.x) row[k] = rel_emb[r * 2 * WD + k];
    __syncthreads();
    int d = threadIdx.x;
    if (d < D) {
        float acc = rel_b[d];
        for (int k = 0; k < 2 * WD; ++k) acc += row[k] * rel_W[d * 2 * WD + k];
        rel_proj[r * D + d] = acc;
    }
}

__global__ void k_self_proj(const float* __restrict__ rel_proj, const float* __restrict__ self_W,
                            const float* __restrict__ self_b, float* __restrict__ self_proj) {
    __shared__ float row[D];
    int r = blockIdx.x, l = blockIdx.y;
    for (int k = threadIdx.x; k < D; k += blockDim.x) row[k] = rel_proj[r * D + k];
    __syncthreads();
    int d = threadIdx.x;
    if (d < D) {
        float acc = self_b[l * D + d];
        for (int k = 0; k < D; ++k) acc += row[k] * self_W[l * D * D + d * D + k];
        self_proj[(l * NREL + r) * D + d] = acc;
    }
}

__global__ void k_xw(const int* __restrict__ qtext, const float* __restrict__ word_emb,
                     const float* __restrict__ Wih, const float* __restrict__ bih,
                     const float* __restrict__ bhh, float* __restrict__ xW) {
    __shared__ float row[WD];
    int bt = blockIdx.x;
    int w = qtext[bt];
    for (int k = threadIdx.x; k < WD; k += blockDim.x) row[k] = word_emb[w * WD + k];
    __syncthreads();
    for (int g = threadIdx.x; g < G4; g += blockDim.x) {
        float acc = bih[g] + bhh[g];
        for (int k = 0; k < WD; ++k) acc += row[k] * Wih[g * WD + k];
        xW[bt * G4 + g] = acc;
    }
}

__global__ void k_lstm(const float* __restrict__ xW, const float* __restrict__ Whh,
                       float* __restrict__ qh) {
    __shared__ float h[D], c[D], gate[G4];
    int b = blockIdx.x;
    if (threadIdx.x < D) { h[threadIdx.x] = 0.f; c[threadIdx.x] = 0.f; }
    __syncthreads();
    for (int t = 0; t < Q; ++t) {
        int g = threadIdx.x;
        if (g < G4) {
            float acc = xW[(b * Q + t) * G4 + g];
            for (int k = 0; k < D; ++k) acc += h[k] * Whh[g * D + k];
            gate[g] = acc;
        }
        __syncthreads();
        int d = threadIdx.x;
        if (d < D) {
            float ig = sigmoidf_(gate[d]);
            float fg = sigmoidf_(gate[D + d]);
            float gg = tanhf(gate[2 * D + d]);
            float og = sigmoidf_(gate[3 * D + d]);
            float cn = fg * c[d] + ig * gg;
            c[d] = cn;
            float hn = og * tanhf(cn);
            h[d] = hn;
            qh[(b * Q + t) * D + d] = hn;
        }
        __syncthreads();
    }
}

__global__ void k_q2e(const float* __restrict__ qh, const float* __restrict__ q2e_W,
                      const float* __restrict__ q2e_b, float* __restrict__ q2e_vec) {
    __shared__ float row[D];
    int b = blockIdx.x, l = blockIdx.y;
    for (int k = threadIdx.x; k < D; k += blockDim.x) row[k] = qh[(b * Q + (Q - 1)) * D + k];
    __syncthreads();
    int d = threadIdx.x;
    if (d < D) {
        float acc = q2e_b[l * D + d];
        for (int k = 0; k < D; ++k) acc += row[k] * q2e_W[l * D * D + d * D + k];
        q2e_vec[(l * B + b) * D + d] = acc;
    }
}

// Wf depends only on (b, rel): 8 x 301 values
__global__ void k_wf_rel(const int* __restrict__ qtext, const float* __restrict__ qh,
                         const float* __restrict__ rel_proj, float* __restrict__ Wf_rel) {
    __shared__ float qh_s[Q * D];
    __shared__ float msk[Q];
    int b = blockIdx.y;
    for (int k = threadIdx.x; k < Q * D; k += blockDim.x) qh_s[k] = qh[b * Q * D + k];
    if (threadIdx.x < Q) msk[threadIdx.x] = (qtext[b * Q + threadIdx.x] != NW) ? 1.f : 0.f;
    __syncthreads();
    int rel = blockIdx.x * 256 + threadIdx.x;
    if (rel >= NREL) return;
    const float* lfe = rel_proj + rel * D;
    float s[Q];
#pragma unroll
    for (int q = 0; q < Q; ++q) s[q] = 0.f;
    for (int k = 0; k < D; ++k) {
        float lv = lfe[k];
#pragma unroll
        for (int q = 0; q < Q; ++q) s[q] += qh_s[q * D + k] * lv;
    }
    float m = -INFINITY;
    float sv[Q];
#pragma unroll
    for (int q = 0; q < Q; ++q) {
        s[q] *= 0.1f;
        sv[q] = s[q] + (1.f - msk[q]) * VERY_NEG;
        m = fmaxf(m, sv[q]);
    }
    float sum = 0.f, wf = 0.f;
    float ex[Q];
#pragma unroll
    for (int q = 0; q < Q; ++q) { ex[q] = expf(sv[q] - m); sum += ex[q]; }
#pragma unroll
    for (int q = 0; q < Q; ++q) wf += (ex[q] / sum) * s[q];
    Wf_rel[b * NREL + rel] = wf;
}

// max over facts (gather through kb_rel) — exact per reference
__global__ void k_wmax(const float* __restrict__ Wf_rel, const int* __restrict__ kb_rel,
                       float* __restrict__ Wmax) {
    __shared__ float red[256];
    int b = blockIdx.x;
    float m = -INFINITY;
    for (int f = threadIdx.x; f < FC; f += 256) m = fmaxf(m, Wf_rel[b * NREL + kb_rel[b * FC + f]]);
    red[threadIdx.x] = m;
    __syncthreads();
    for (int s = 128; s > 0; s >>= 1) {
        if (threadIdx.x < s) red[threadIdx.x] = fmaxf(red[threadIdx.x], red[threadIdx.x + s]);
        __syncthreads();
    }
    if (threadIdx.x == 0) Wmax[b] = red[0];
}

__global__ void k_wt_rel(const float* __restrict__ Wf_rel, const float* __restrict__ Wmax,
                         float* __restrict__ Wt_rel) {
    int b = blockIdx.y;
    int rel = blockIdx.x * 256 + threadIdx.x;
    if (rel >= NREL) return;
    Wt_rel[b * NREL + rel] = expf(Wf_rel[b * NREL + rel] - Wmax[b]);
}

__global__ void k_e2fsm(const float* __restrict__ Wt_rel, const int* __restrict__ kb_rel,
                        const int* __restrict__ e2f, float* __restrict__ W_tilde,
                        float* __restrict__ e2f_sm) {
    int fid = blockIdx.x * 256 + threadIdx.x;
    if (fid >= NF) return;
    int b = fid / FC;
    float wt = Wt_rel[b * NREL + kb_rel[fid]];
    W_tilde[fid] = wt;
    atomicAdd(&e2f_sm[b * E + e2f[fid]], wt);
}

// ================= counting sort by destination (b, f2e) =================

__global__ void k_hist(const int* __restrict__ f2e, int* __restrict__ cnt) {
    int fid = blockIdx.x * 256 + threadIdx.x;
    if (fid >= NF) return;
    int ri = (fid / FC) * E + f2e[fid];
    atomicAdd(&cnt[ri], 1);
}

__global__ void k_scan(const int* __restrict__ cnt, int* __restrict__ off, int* __restrict__ cursor) {
    __shared__ int part[256];
    constexpr int CH = (NR_ + 255) / 256;
    int t = threadIdx.x;
    int base = t * CH;
    int s = 0;
    for (int i = 0; i < CH; ++i) {
        int idx = base + i;
        if (idx < NR_) s += cnt[idx];
    }
    part[t] = s;
    __syncthreads();
    for (int d = 1; d < 256; d <<= 1) {
        int add = (t >= d) ? part[t - d] : 0;
        __syncthreads();
        part[t] += add;
        __syncthreads();
    }
    int run = part[t] - s;
    for (int i = 0; i < CH; ++i) {
        int idx = base + i;
        if (idx < NR_) {
            off[idx] = run;
            cursor[idx] = run;
            run += cnt[idx];
        }
    }
    if (t == 255) off[NR_] = part[255];
}

__global__ void k_scatter(const int* __restrict__ f2e, int* __restrict__ cursor,
                          int* __restrict__ sorted_fid) {
    int fid = blockIdx.x * 256 + threadIdx.x;
    if (fid >= NF) return;
    int ri = (fid / FC) * E + f2e[fid];
    int pos = atomicAdd(&cursor[ri], 1);
    sorted_fid[pos] = fid;
}

__global__ void k_cntf(const int* __restrict__ off, float* __restrict__ cnt_f) {
    int i = blockIdx.x * 256 + threadIdx.x;
    if (i < NR_) cnt_f[i] = (float)(off[i + 1] - off[i]);
}

// ================= per-layer fact kernels =================

__global__ void k_n(const float* __restrict__ W_tilde, const float* __restrict__ pr,
                    const float* __restrict__ e2f_sm, const int* __restrict__ e2f,
                    float* __restrict__ n) {
    int fid = blockIdx.x * 256 + threadIdx.x;
    if (fid >= NF) return;
    int b = fid / FC;
    int es = e2f[fid];
    n[fid] = W_tilde[fid] * pr[b * E + es] / fmaxf(e2f_sm[b * E + es], VERY_SMALLF);
}

__global__ void k_gather(const int* __restrict__ sorted_fid, const int* __restrict__ off,
                         const float* __restrict__ n, const int* __restrict__ kb_rel,
                         const int* __restrict__ e2f, const float* __restrict__ self_proj,
                         const float* __restrict__ head, int l,
                         float* __restrict__ u, float* __restrict__ pr_acc) {
    int wave = threadIdx.x >> 6, lane = threadIdx.x & 63;
    int ri = blockIdx.x * 4 + wave;
    int b = ri / E;
    int s = off[ri], e = off[ri + 1];
    float a0 = 0.f, a1 = 0.f, ns = 0.f;
    const float* spb = self_proj + l * NREL * D;
    const float* hb = head + b * E * D;
    for (int j = s; j < e; ++j) {
        int fid = sorted_fid[j];
        float nj = n[fid];
        int rel = kb_rel[fid];
        int es = e2f[fid];
        const float* sp = spb + rel * D;
        const float* hr = hb + es * D;
        a0 += nj * fmaxf(0.f, sp[lane] + hr[lane]);
        if (lane < D - 64) a1 += nj * fmaxf(0.f, sp[lane + 64] + hr[lane + 64]);
        ns += nj;
    }
    u[ri * D + lane] = a0;
    if (lane < D - 64) u[ri * D + 64 + lane] = a1;
    if (lane == 0) pr_acc[ri] = ns;
}

__global__ void k_score(const int* __restrict__ local_entity, const float* __restrict__ lee,
                        const float* __restrict__ score_W, const float* __restrict__ score_b,
                        float* __restrict__ out) {
    int i = blockIdx.x * 256 + threadIdx.x;
    if (i >= B * E) return;
    if (local_entity[i] == NE) { out[i] = 0.f; return; }
    float acc = score_b[0];
    for (int k = 0; k < D; ++k) acc += lee[i * D + k] * score_W[k];
    out[i] = 1.f / (1.f + expf(-acc));
}

extern "C" void kernel_launch(void* const* d_in, const int* in_sizes, int n_in,
                              void* d_out, int out_size, void* d_ws, size_t ws_size,
                              hipStream_t stream) {
    const int*   local_entity = (const int*)d_in[0];
    const float* q2e_adj      = (const float*)d_in[1];
    const int*   kb_rel       = (const int*)d_in[2];
    const int*   qtext        = (const int*)d_in[3];
    const int*   e2f          = (const int*)d_in[4];
    const int*   f2e          = (const int*)d_in[5];
    const float* word_emb     = (const float*)d_in[7];
    const float* entity_emb   = (const float*)d_in[8];
    const float* rel_emb      = (const float*)d_in[9];
    const float* ent_W        = (const float*)d_in[10];
    const float* ent_b        = (const float*)d_in[11];
    const float* rel_W        = (const float*)d_in[12];
    const float* rel_b        = (const float*)d_in[13];
    const float* lstm_Wih     = (const float*)d_in[14];
    const float* lstm_Whh     = (const float*)d_in[15];
    const float* lstm_bih     = (const float*)d_in[16];
    const float* lstm_bhh     = (const float*)d_in[17];
    const float* q2e_W        = (const float*)d_in[18];
    const float* q2e_b        = (const float*)d_in[19];
    const float* head_W       = (const float*)d_in[20];
    const float* head_b       = (const float*)d_in[21];
    const float* tail_W       = (const float*)d_in[22];
    const float* tail_b       = (const float*)d_in[23];
    const float* self_W       = (const float*)d_in[24];
    const float* self_b       = (const float*)d_in[25];
    const float* e2e_W        = (const float*)d_in[26];
    const float* e2e_b        = (const float*)d_in[27];
    const float* score_W      = (const float*)d_in[28];
    const float* score_b      = (const float*)d_in[29];

    float* ws = (float*)d_ws;
    float* rel_proj  = ws;                       // 30100
    float* self_proj = rel_proj  + NREL * D;     // 90300
    float* xW        = self_proj + 3 * NREL * D; // 64000
    float* qh        = xW        + B * Q * G4;   // 16000
    float* q2e_vec   = qh        + B * Q * D;    // 2400
    float* Wf_rel    = q2e_vec   + 3 * B * D;    // 2408
    float* Wt_rel    = Wf_rel    + B * NREL;     // 2408
    float* Wmax      = Wt_rel    + B * NREL;     // 8
    float* W_tilde   = Wmax      + 8;            // 96000
    float* e2f_sm    = W_tilde   + NF;           // 16000
    float* leeA      = e2f_sm    + NR_;          // 1.6M
    float* leeB      = leeA      + NR_ * D;
    float* head      = leeB      + NR_ * D;
    float* lee_self  = head      + NR_ * D;
    float* f2e_acc   = lee_self  + NR_ * D;
    float* u_buf     = f2e_acc   + NR_ * D;
    float* pr        = u_buf     + NR_ * D;      // 16000
    float* pr_acc    = pr        + NR_;          // 16000
    float* n_buf     = pr_acc    + NR_;          // 96000
    float* cnt_f     = n_buf     + NF;           // 16000
    int*   cnt       = (int*)(cnt_f + NR_);      // 16000
    int*   cursor    = cnt       + NR_;
    int*   off       = cursor    + NR_;          // 16001
    int*   sorted    = off       + NR_ + 1;      // 96000

    hipMemcpyAsync(pr, q2e_adj, (size_t)NR_ * sizeof(float), hipMemcpyDeviceToDevice, stream);
    hipMemsetAsync(cnt, 0, NR_ * sizeof(int), stream);
    hipMemsetAsync(e2f_sm, 0, (size_t)NR_ * sizeof(float), stream);

    k_hist<<<(NF + 255) / 256, 256, 0, stream>>>(f2e, cnt);
    k_scan<<<1, 256, 0, stream>>>(cnt, off, cursor);
    k_scatter<<<(NF + 255) / 256, 256, 0, stream>>>(f2e, cursor, sorted);
    k_cntf<<<(NR_ + 255) / 256, 256, 0, stream>>>(off, cnt_f);

    k_rel_proj<<<NREL, 128, 0, stream>>>(rel_emb, rel_W, rel_b, rel_proj);
    k_self_proj<<<dim3(NREL, 3), 128, 0, stream>>>(rel_proj, self_W, self_b, self_proj);
    k_xw<<<B * Q, 256, 0, stream>>>(qtext, word_emb, lstm_Wih, lstm_bih, lstm_bhh, xW);
    k_lstm<<<B, 512, 0, stream>>>(xW, lstm_Whh, qh);
    k_q2e<<<dim3(B, 3), 128, 0, stream>>>(qh, q2e_W, q2e_b, q2e_vec);
    k_wf_rel<<<dim3(2, B), 256, 0, stream>>>(qtext, qh, rel_proj, Wf_rel);
    k_wmax<<<B, 256, 0, stream>>>(Wf_rel, kb_rel, Wmax);
    k_wt_rel<<<dim3(2, B), 256, 0, stream>>>(Wf_rel, Wmax, Wt_rel);
    k_e2fsm<<<(NF + 255) / 256, 256, 0, stream>>>(Wt_rel, kb_rel, e2f, W_tilde, e2f_sm);

    // local_entity_emb = entity_emb[local_entity] @ ent_W^T + ent_b  (gather fused)
    k_gemm<WD, 0><<<NR_ / BR, 256, 0, stream>>>(entity_emb, ent_W, ent_b, nullptr, local_entity, leeA);

    float* cur = leeA; float* nxt = leeB;
    for (int l = 0; l < 3; ++l) {
        k_gemm<D, 0><<<NR_ / BR, 256, 0, stream>>>(cur, head_W + l * D * D, head_b + l * D,
                                                   nullptr, nullptr, head);
        k_gemm<D, 0><<<NR_ / BR, 256, 0, stream>>>(cur, self_W + l * D * D, self_b + l * D,
                                                   nullptr, nullptr, lee_self);
        k_n<<<(NF + 255) / 256, 256, 0, stream>>>(W_tilde, pr, e2f_sm, e2f, n_buf);
        k_gather<<<NR_ / 4, 256, 0, stream>>>(sorted, off, n_buf, kb_rel, e2f, self_proj, head, l,
                                              u_buf, pr_acc);
        k_gemm<D, 0><<<NR_ / BR, 256, 0, stream>>>(u_buf, tail_W + l * D * D, tail_b + l * D,
                                                   cnt_f, nullptr, f2e_acc);
        k_gemm_ent<<<NR_ / BR, 256, 0, stream>>>(cur, lee_self, f2e_acc, q2e_vec + l * B * D,
                                                 e2e_W + l * D * 3 * D, e2e_b + l * D,
                                                 pr_acc, pr, nxt);
        float* tmp = cur; cur = nxt; nxt = tmp;
    }
    k_score<<<(B * E + 255) / 256, 256, 0, stream>>>(local_entity, cur, score_W, score_b, (float*)d_out);
}

// Round 4
// 569.444 us; speedup vs baseline: 3.4889x; 1.2596x over previous
//
#include <hip/hip_runtime.h>
#include <math.h>

#define VERY_NEG  -100000000000.0f
#define VERY_SMALLF 1e-10f

constexpr int B  = 8;
constexpr int E  = 2000;
constexpr int FC = 12000;
constexpr int Q  = 20;
constexpr int WD = 300;
constexpr int D  = 100;
constexpr int NW = 40000;
constexpr int NE = 100000;
constexpr int G4 = 4 * D;   // 400
constexpr int NREL = 301;
constexpr int NF = B * FC;  // 96000
constexpr int NR_ = B * E;  // 16000 rows

__device__ __forceinline__ float sigmoidf_(float x) { return 1.0f / (1.0f + expf(-x)); }

// ---------------- transpose: out[z][k][m] = in[z][m][k], block (32,8) ----------------
__global__ void k_tr(const float* __restrict__ in, float* __restrict__ out, int M, int K) {
    __shared__ float t[32][33];
    size_t zo = (size_t)blockIdx.z * M * K;
    int k0 = blockIdx.x * 32, m0 = blockIdx.y * 32;
    int x = threadIdx.x, y = threadIdx.y;
    for (int yy = y; yy < 32; yy += 8) {
        int m = m0 + yy, k = k0 + x;
        if (m < M && k < K) t[yy][x] = in[zo + (size_t)m * K + k];
    }
    __syncthreads();
    for (int yy = y; yy < 32; yy += 8) {
        int k = k0 + yy, m = m0 + x;
        if (m < M && k < K) out[zo + (size_t)k * M + m] = t[x][yy];
    }
}

__global__ void k_bihh(const float* __restrict__ a, const float* __restrict__ b, float* __restrict__ o) {
    int i = threadIdx.x;
    if (i < G4) o[i] = a[i] + b[i];
}

// ---------------- GEMM building blocks ----------------
// As layout: [32 rows][104] row-major (pad 104 keeps float4 alignment, spreads banks)
// Bs layout: [100 k][100 d] row-major (Wt is pre-transposed [K][ldW])

__device__ __forceinline__ void stage_rows_id(const float* __restrict__ A, int stride, int base,
                                              int k0, float* __restrict__ dst) {
    for (int i = threadIdx.x; i < 800; i += 256) {
        int r = i / 25, c = i - r * 25;
        *(float4*)&dst[r * 104 + c * 4] = *(const float4*)&A[(size_t)(base + r) * stride + k0 + c * 4];
    }
}

__device__ __forceinline__ void stage_B(const float* __restrict__ Wt, int ldW, int col0, int k0,
                                        float* __restrict__ dst) {
    for (int i = threadIdx.x; i < 2500; i += 256) {
        int k = i / 25, d = i - k * 25;
        *(float4*)&dst[k * 100 + d * 4] = *(const float4*)&Wt[(size_t)(k0 + k) * ldW + col0 + d * 4];
    }
}

__device__ __forceinline__ void tile16(const float* __restrict__ As_, const float* __restrict__ Bs_,
                                       int rg, int cgc, float acc[4][4]) {
#pragma unroll 5
    for (int k4 = 0; k4 < 25; ++k4) {
        float a_[4][4], b_[4][4];
#pragma unroll
        for (int i = 0; i < 4; ++i) {
            float4 v = *(const float4*)&As_[(rg * 4 + i) * 104 + k4 * 4];
            a_[i][0] = v.x; a_[i][1] = v.y; a_[i][2] = v.z; a_[i][3] = v.w;
        }
#pragma unroll
        for (int kk = 0; kk < 4; ++kk) {
            float4 v = *(const float4*)&Bs_[(k4 * 4 + kk) * 100 + cgc * 4];
            b_[kk][0] = v.x; b_[kk][1] = v.y; b_[kk][2] = v.z; b_[kk][3] = v.w;
        }
#pragma unroll
        for (int kk = 0; kk < 4; ++kk)
#pragma unroll
            for (int i = 0; i < 4; ++i)
#pragma unroll
                for (int j = 0; j < 4; ++j)
                    acc[i][j] += a_[i][kk] * b_[kk][j];
    }
}

// generic: C[r, col0:col0+100] = act(A[rix[r], :] @ Wt + bias), grid (rowblocks, colchunks)
template<int K, int ACT>
__global__ __launch_bounds__(256) void k_gemm(const float* __restrict__ A,
                                              const float* __restrict__ Wt,
                                              const float* __restrict__ bias,
                                              const int* __restrict__ row_idx,
                                              float* __restrict__ C, int ldW, int nrows) {
    __shared__ float As_[32 * 104];
    __shared__ float Bs_[100 * 100];
    __shared__ int rix[32];
    int tid = threadIdx.x, base = blockIdx.x * 32, col0 = blockIdx.y * 100;
    if (tid < 32) {
        int r = base + tid;
        if (r > nrows - 1) r = nrows - 1;
        rix[tid] = row_idx ? row_idx[r] : r;
    }
    int cg = tid & 31, rg = tid >> 5, cgc = cg < 25 ? cg : 24;
    float acc[4][4];
#pragma unroll
    for (int i = 0; i < 4; ++i)
#pragma unroll
        for (int j = 0; j < 4; ++j) acc[i][j] = 0.f;
    for (int k0 = 0; k0 < K; k0 += 100) {
        __syncthreads();
        for (int i = tid; i < 800; i += 256) {
            int r = i / 25, c = i - r * 25;
            *(float4*)&As_[r * 104 + c * 4] = *(const float4*)&A[(size_t)rix[r] * K + k0 + c * 4];
        }
        stage_B(Wt, ldW, col0, k0, Bs_);
        __syncthreads();
        tile16(As_, Bs_, rg, cgc, acc);
    }
    if (cg < 25) {
        float4 bb = *(const float4*)&bias[col0 + cg * 4];
#pragma unroll
        for (int i = 0; i < 4; ++i) {
            int r = base + rg * 4 + i;
            if (r < nrows) {
                float4 o;
                o.x = acc[i][0] + bb.x; o.y = acc[i][1] + bb.y;
                o.z = acc[i][2] + bb.z; o.w = acc[i][3] + bb.w;
                if (ACT) { o.x = fmaxf(o.x, 0.f); o.y = fmaxf(o.y, 0.f); o.z = fmaxf(o.z, 0.f); o.w = fmaxf(o.w, 0.f); }
                *(float4*)&C[(size_t)r * ldW + col0 + cg * 4] = o;
            }
        }
    }
}

// head+self fused: one A staging, two weight matrices (K=100, 16000 rows exact)
__global__ __launch_bounds__(256) void k_gemm_dual(const float* __restrict__ A,
                                                   const float* __restrict__ W1t, const float* __restrict__ b1,
                                                   float* __restrict__ C1,
                                                   const float* __restrict__ W2t, const float* __restrict__ b2,
                                                   float* __restrict__ C2) {
    __shared__ float As_[32 * 104];
    __shared__ float Bs_[100 * 100];
    int tid = threadIdx.x, base = blockIdx.x * 32;
    int cg = tid & 31, rg = tid >> 5, cgc = cg < 25 ? cg : 24;
    stage_rows_id(A, 100, base, 0, As_);
    stage_B(W1t, 100, 0, 0, Bs_);
    __syncthreads();
    float acc[4][4];
#pragma unroll
    for (int i = 0; i < 4; ++i)
#pragma unroll
        for (int j = 0; j < 4; ++j) acc[i][j] = 0.f;
    tile16(As_, Bs_, rg, cgc, acc);
    if (cg < 25) {
        float4 bb = *(const float4*)&b1[cg * 4];
#pragma unroll
        for (int i = 0; i < 4; ++i) {
            int r = base + rg * 4 + i;
            float4 o;
            o.x = acc[i][0] + bb.x; o.y = acc[i][1] + bb.y;
            o.z = acc[i][2] + bb.z; o.w = acc[i][3] + bb.w;
            *(float4*)&C1[(size_t)r * 100 + cg * 4] = o;
        }
    }
    __syncthreads();
    stage_B(W2t, 100, 0, 0, Bs_);
    __syncthreads();
#pragma unroll
    for (int i = 0; i < 4; ++i)
#pragma unroll
        for (int j = 0; j < 4; ++j) acc[i][j] = 0.f;
    tile16(As_, Bs_, rg, cgc, acc);
    if (cg < 25) {
        float4 bb = *(const float4*)&b2[cg * 4];
#pragma unroll
        for (int i = 0; i < 4; ++i) {
            int r = base + rg * 4 + i;
            float4 o;
            o.x = acc[i][0] + bb.x; o.y = acc[i][1] + bb.y;
            o.z = acc[i][2] + bb.z; o.w = acc[i][3] + bb.w;
            *(float4*)&C2[(size_t)r * 100 + cg * 4] = o;
        }
    }
}

// fused tail-GEMM + entity-update GEMM + pagerank update
__global__ __launch_bounds__(256) void k_tailent(const float* __restrict__ u,
                                                 const float* __restrict__ cnt_f,
                                                 const float* __restrict__ tailWt_l,
                                                 const float* __restrict__ tail_b_l,
                                                 const float* __restrict__ cur,
                                                 const float* __restrict__ lee_self,
                                                 const float* __restrict__ q2e_l,
                                                 const float* __restrict__ e2eWt_l,
                                                 const float* __restrict__ e2e_b_l,
                                                 const float* __restrict__ pr_acc,
                                                 float* __restrict__ pr,
                                                 float* __restrict__ nxt) {
    __shared__ float As_[32 * 104];
    __shared__ float Bs_[100 * 100];
    __shared__ float Fs_[32 * 104];
    int tid = threadIdx.x, base = blockIdx.x * 32;
    int cg = tid & 31, rg = tid >> 5, cgc = cg < 25 ? cg : 24;
    // phase 1: f2e block = u @ tailWt + cnt*tail_b ; Fs = 3*relu(lee_self + f2e)
    stage_rows_id(u, 100, base, 0, As_);
    stage_B(tailWt_l, 100, 0, 0, Bs_);
    __syncthreads();
    float accF[4][4];
#pragma unroll
    for (int i = 0; i < 4; ++i)
#pragma unroll
        for (int j = 0; j < 4; ++j) accF[i][j] = 0.f;
    tile16(As_, Bs_, rg, cgc, accF);
    if (cg < 25) {
        float4 tb = *(const float4*)&tail_b_l[cg * 4];
#pragma unroll
        for (int i = 0; i < 4; ++i) {
            int r = base + rg * 4 + i;
            float cf = cnt_f[r];
            float4 ls = *(const float4*)&lee_self[(size_t)r * 100 + cg * 4];
            float4 o;
            o.x = 3.f * fmaxf(0.f, ls.x + accF[i][0] + cf * tb.x);
            o.y = 3.f * fmaxf(0.f, ls.y + accF[i][1] + cf * tb.y);
            o.z = 3.f * fmaxf(0.f, ls.z + accF[i][2] + cf * tb.z);
            o.w = 3.f * fmaxf(0.f, ls.w + accF[i][3] + cf * tb.w);
            *(float4*)&Fs_[(rg * 4 + i) * 104 + cg * 4] = o;
        }
    }
    if (tid < 32) {
        int r = base + tid;
        pr[r] = 0.8f * pr_acc[r] + 0.2f * pr[r];
    }
    __syncthreads();
    // phase 2: ent GEMM over K=300 in 3 chunks: lee, q2e, Fs
    float acc[4][4];
#pragma unroll
    for (int i = 0; i < 4; ++i)
#pragma unroll
        for (int j = 0; j < 4; ++j) acc[i][j] = 0.f;
    stage_rows_id(cur, 100, base, 0, As_);
    stage_B(e2eWt_l, 100, 0, 0, Bs_);
    __syncthreads();
    tile16(As_, Bs_, rg, cgc, acc);
    __syncthreads();
    for (int i = tid; i < 800; i += 256) {
        int r = i / 25, c = i - r * 25;
        int b = (base + r) / E;
        *(float4*)&As_[r * 104 + c * 4] = *(const float4*)&q2e_l[b * 100 + c * 4];
    }
    stage_B(e2eWt_l, 100, 0, 100, Bs_);
    __syncthreads();
    tile16(As_, Bs_, rg, cgc, acc);
    __syncthreads();
    stage_B(e2eWt_l, 100, 0, 200, Bs_);
    __syncthreads();
    tile16(Fs_, Bs_, rg, cgc, acc);
    if (cg < 25) {
        float4 eb = *(const float4*)&e2e_b_l[cg * 4];
#pragma unroll
        for (int i = 0; i < 4; ++i) {
            int r = base + rg * 4 + i;
            float4 o;
            o.x = fmaxf(acc[i][0] + eb.x, 0.f); o.y = fmaxf(acc[i][1] + eb.y, 0.f);
            o.z = fmaxf(acc[i][2] + eb.z, 0.f); o.w = fmaxf(acc[i][3] + eb.w, 0.f);
            *(float4*)&nxt[(size_t)r * 100 + cg * 4] = o;
        }
    }
}

// ---------------- LSTM (recurrent, uses transposed Whh for coalesced reads) ----------------
__global__ void k_lstm(const float* __restrict__ xW, const float* __restrict__ WhhT,
                       float* __restrict__ qh) {
    __shared__ float h[D], c[D], gate[G4];
    int b = blockIdx.x;
    if (threadIdx.x < D) { h[threadIdx.x] = 0.f; c[threadIdx.x] = 0.f; }
    __syncthreads();
    for (int t = 0; t < Q; ++t) {
        int g = threadIdx.x;
        if (g < G4) {
            float acc = xW[(b * Q + t) * G4 + g];
            for (int k = 0; k < D; ++k) acc += h[k] * WhhT[k * G4 + g];
            gate[g] = acc;
        }
        __syncthreads();
        int d = threadIdx.x;
        if (d < D) {
            float ig = sigmoidf_(gate[d]);
            float fg = sigmoidf_(gate[D + d]);
            float gg = tanhf(gate[2 * D + d]);
            float og = sigmoidf_(gate[3 * D + d]);
            float cn = fg * c[d] + ig * gg;
            c[d] = cn;
            float hn = og * tanhf(cn);
            h[d] = hn;
            qh[(b * Q + t) * D + d] = hn;
        }
        __syncthreads();
    }
}

__global__ void k_q2e(const float* __restrict__ qh, const float* __restrict__ q2e_W,
                      const float* __restrict__ q2e_b, float* __restrict__ q2e_vec) {
    __shared__ float row[D];
    int b = blockIdx.x, l = blockIdx.y;
    for (int k = threadIdx.x; k < D; k += blockDim.x) row[k] = qh[(b * Q + (Q - 1)) * D + k];
    __syncthreads();
    int d = threadIdx.x;
    if (d < D) {
        float acc = q2e_b[l * D + d];
        for (int k = 0; k < D; ++k) acc += row[k] * q2e_W[l * D * D + d * D + k];
        q2e_vec[(l * B + b) * D + d] = acc;
    }
}

// ---------------- Wf (per (b, rel), 8x301 distinct) ----------------
__global__ void k_wf_rel(const int* __restrict__ qtext, const float* __restrict__ qh,
                         const float* __restrict__ rel_proj, float* __restrict__ Wf_rel) {
    __shared__ float qh_s[Q * D];
    __shared__ float msk[Q];
    int b = blockIdx.y;
    for (int k = threadIdx.x; k < Q * D; k += blockDim.x) qh_s[k] = qh[b * Q * D + k];
    if (threadIdx.x < Q) msk[threadIdx.x] = (qtext[b * Q + threadIdx.x] != NW) ? 1.f : 0.f;
    __syncthreads();
    int rel = blockIdx.x * 256 + threadIdx.x;
    if (rel >= NREL) return;
    const float* lfe = rel_proj + rel * D;
    float s[Q];
#pragma unroll
    for (int q = 0; q < Q; ++q) s[q] = 0.f;
    for (int k = 0; k < D; ++k) {
        float lv = lfe[k];
#pragma unroll
        for (int q = 0; q < Q; ++q) s[q] += qh_s[q * D + k] * lv;
    }
    float m = -INFINITY;
    float sv[Q];
#pragma unroll
    for (int q = 0; q < Q; ++q) {
        s[q] *= 0.1f;
        sv[q] = s[q] + (1.f - msk[q]) * VERY_NEG;
        m = fmaxf(m, sv[q]);
    }
    float sum = 0.f, wf = 0.f;
    float ex[Q];
#pragma unroll
    for (int q = 0; q < Q; ++q) { ex[q] = expf(sv[q] - m); sum += ex[q]; }
#pragma unroll
    for (int q = 0; q < Q; ++q) wf += (ex[q] / sum) * s[q];
    Wf_rel[b * NREL + rel] = wf;
}

__global__ void k_wmax(const float* __restrict__ Wf_rel, const int* __restrict__ kb_rel,
                       float* __restrict__ Wmax) {
    __shared__ float red[256];
    int b = blockIdx.x;
    float m = -INFINITY;
    for (int f = threadIdx.x; f < FC; f += 256) m = fmaxf(m, Wf_rel[b * NREL + kb_rel[b * FC + f]]);
    red[threadIdx.x] = m;
    __syncthreads();
    for (int s = 128; s > 0; s >>= 1) {
        if (threadIdx.x < s) red[threadIdx.x] = fmaxf(red[threadIdx.x], red[threadIdx.x + s]);
        __syncthreads();
    }
    if (threadIdx.x == 0) Wmax[b] = red[0];
}

__global__ void k_wt_rel(const float* __restrict__ Wf_rel, const float* __restrict__ Wmax,
                         float* __restrict__ Wt_rel) {
    int b = blockIdx.y;
    int rel = blockIdx.x * 256 + threadIdx.x;
    if (rel >= NREL) return;
    Wt_rel[b * NREL + rel] = expf(Wf_rel[b * NREL + rel] - Wmax[b]);
}

__global__ void k_e2fsm(const float* __restrict__ Wt_rel, const int* __restrict__ kb_rel,
                        const int* __restrict__ e2f, float* __restrict__ W_tilde,
                        float* __restrict__ e2f_sm) {
    int fid = blockIdx.x * 256 + threadIdx.x;
    if (fid >= NF) return;
    int b = fid / FC;
    float wt = Wt_rel[b * NREL + kb_rel[fid]];
    W_tilde[fid] = wt;
    atomicAdd(&e2f_sm[b * E + e2f[fid]], wt);
}

// ---------------- counting sort by destination (b, f2e) ----------------
__global__ void k_hist(const int* __restrict__ f2e, int* __restrict__ cnt) {
    int fid = blockIdx.x * 256 + threadIdx.x;
    if (fid >= NF) return;
    int ri = (fid / FC) * E + f2e[fid];
    atomicAdd(&cnt[ri], 1);
}

__global__ void k_scan(const int* __restrict__ cnt, int* __restrict__ off, int* __restrict__ cursor) {
    __shared__ int part[256];
    constexpr int CH = (NR_ + 255) / 256;
    int t = threadIdx.x;
    int base = t * CH;
    int s = 0;
    for (int i = 0; i < CH; ++i) {
        int idx = base + i;
        if (idx < NR_) s += cnt[idx];
    }
    part[t] = s;
    __syncthreads();
    for (int d = 1; d < 256; d <<= 1) {
        int add = (t >= d) ? part[t - d] : 0;
        __syncthreads();
        part[t] += add;
        __syncthreads();
    }
    int run = part[t] - s;
    for (int i = 0; i < CH; ++i) {
        int idx = base + i;
        if (idx < NR_) {
            off[idx] = run;
            cursor[idx] = run;
            run += cnt[idx];
        }
    }
    if (t == 255) off[NR_] = part[255];
}

__global__ void k_scatter(const int* __restrict__ f2e, int* __restrict__ cursor,
                          int* __restrict__ sorted_fid) {
    int fid = blockIdx.x * 256 + threadIdx.x;
    if (fid >= NF) return;
    int ri = (fid / FC) * E + f2e[fid];
    int pos = atomicAdd(&cursor[ri], 1);
    sorted_fid[pos] = fid;
}

__global__ void k_cntf(const int* __restrict__ off, float* __restrict__ cnt_f) {
    int i = blockIdx.x * 256 + threadIdx.x;
    if (i < NR_) cnt_f[i] = (float)(off[i + 1] - off[i]);
}

// ---------------- gather (n computed inline) ----------------
__global__ void k_gather(const int* __restrict__ sorted_fid, const int* __restrict__ off,
                         const float* __restrict__ W_tilde, const float* __restrict__ pr,
                         const float* __restrict__ e2f_sm, const int* __restrict__ kb_rel,
                         const int* __restrict__ e2f, const float* __restrict__ self_proj,
                         const float* __restrict__ head, int l,
                         float* __restrict__ u, float* __restrict__ pr_acc) {
    int wave = threadIdx.x >> 6, lane = threadIdx.x & 63;
    int ri = blockIdx.x * 4 + wave;
    int b = ri / E;
    int bE = b * E;
    int s = off[ri], e = off[ri + 1];
    float a0 = 0.f, a1 = 0.f, ns = 0.f;
    const float* spb = self_proj + l * NREL * D;
    const float* hb = head + (size_t)bE * D;
    for (int j = s; j < e; ++j) {
        int fid = sorted_fid[j];
        int rel = kb_rel[fid];
        int es = e2f[fid];
        float nj = W_tilde[fid] * pr[bE + es] / fmaxf(e2f_sm[bE + es], VERY_SMALLF);
        const float* sp = spb + rel * D;
        const float* hr = hb + (size_t)es * D;
        a0 += nj * fmaxf(0.f, sp[lane] + hr[lane]);
        if (lane < D - 64) a1 += nj * fmaxf(0.f, sp[lane + 64] + hr[lane + 64]);
        ns += nj;
    }
    u[(size_t)ri * D + lane] = a0;
    if (lane < D - 64) u[(size_t)ri * D + 64 + lane] = a1;
    if (lane == 0) pr_acc[ri] = ns;
}

__global__ void k_score(const int* __restrict__ local_entity, const float* __restrict__ lee,
                        const float* __restrict__ score_W, const float* __restrict__ score_b,
                        float* __restrict__ out) {
    int i = blockIdx.x * 256 + threadIdx.x;
    if (i >= B * E) return;
    if (local_entity[i] == NE) { out[i] = 0.f; return; }
    float acc = score_b[0];
    for (int k = 0; k < D; ++k) acc += lee[i * D + k] * score_W[k];
    out[i] = 1.f / (1.f + expf(-acc));
}

extern "C" void kernel_launch(void* const* d_in, const int* in_sizes, int n_in,
                              void* d_out, int out_size, void* d_ws, size_t ws_size,
                              hipStream_t stream) {
    const int*   local_entity = (const int*)d_in[0];
    const float* q2e_adj      = (const float*)d_in[1];
    const int*   kb_rel       = (const int*)d_in[2];
    const int*   qtext        = (const int*)d_in[3];
    const int*   e2f          = (const int*)d_in[4];
    const int*   f2e          = (const int*)d_in[5];
    const float* word_emb     = (const float*)d_in[7];
    const float* entity_emb   = (const float*)d_in[8];
    const float* rel_emb      = (const float*)d_in[9];
    const float* ent_W        = (const float*)d_in[10];
    const float* ent_b        = (const float*)d_in[11];
    const float* rel_W        = (const float*)d_in[12];
    const float* rel_b        = (const float*)d_in[13];
    const float* lstm_Wih     = (const float*)d_in[14];
    const float* lstm_Whh     = (const float*)d_in[15];
    const float* lstm_bih     = (const float*)d_in[16];
    const float* lstm_bhh     = (const float*)d_in[17];
    const float* q2e_W        = (const float*)d_in[18];
    const float* q2e_b        = (const float*)d_in[19];
    const float* head_W       = (const float*)d_in[20];
    const float* head_b       = (const float*)d_in[21];
    const float* tail_W       = (const float*)d_in[22];
    const float* tail_b       = (const float*)d_in[23];
    const float* self_W       = (const float*)d_in[24];
    const float* self_b       = (const float*)d_in[25];
    const float* e2e_W        = (const float*)d_in[26];
    const float* e2e_b        = (const float*)d_in[27];
    const float* score_W      = (const float*)d_in[28];
    const float* score_b      = (const float*)d_in[29];

    float* ws = (float*)d_ws;
    float* rel_proj  = ws;                       // 30100
    float* self_proj = rel_proj  + NREL * D;     // 90300
    float* xW        = self_proj + 3 * NREL * D; // 64000
    float* qh        = xW        + B * Q * G4;   // 16000
    float* q2e_vec   = qh        + B * Q * D;    // 2400
    float* Wf_rel    = q2e_vec   + 3 * B * D;    // 2408
    float* Wt_rel    = Wf_rel    + B * NREL;     // 2408
    float* Wmax      = Wt_rel    + B * NREL;     // 8
    float* W_tilde   = Wmax      + 8;            // 96000
    float* e2f_sm    = W_tilde   + NF;           // 16000
    float* leeA      = e2f_sm    + NR_;          // 1.6M
    float* leeB      = leeA      + NR_ * D;
    float* head      = leeB      + NR_ * D;
    float* lee_self  = head      + NR_ * D;
    float* u_buf     = lee_self  + NR_ * D;
    float* pr        = u_buf     + NR_ * D;      // 16000
    float* pr_acc    = pr        + NR_;          // 16000
    float* cnt_f     = pr_acc    + NR_;          // 16000
    float* entWt     = cnt_f     + NR_;          // 30000  [300][100]
    float* relWt     = entWt     + WD * D;       // 60000  [600][100]
    float* WihT      = relWt     + 2 * WD * D;   // 120000 [300][400]
    float* WhhT      = WihT      + WD * G4;      // 40000  [100][400]
    float* headWt    = WhhT      + D * G4;       // 30000  [3][100][100]
    float* selfWt    = headWt    + 3 * D * D;    // 30000
    float* tailWt    = selfWt    + 3 * D * D;    // 30000
    float* e2eWt     = tailWt    + 3 * D * D;    // 90000  [3][300][100]
    float* bihh      = e2eWt     + 3 * 3 * D * D;// 400
    int*   cnt       = (int*)(bihh + G4);        // 16000
    int*   cursor    = cnt       + NR_;
    int*   off       = cursor    + NR_;          // 16001
    int*   sorted    = off       + NR_ + 1;      // 96000

    hipMemcpyAsync(pr, q2e_adj, (size_t)NR_ * sizeof(float), hipMemcpyDeviceToDevice, stream);
    hipMemsetAsync(cnt, 0, NR_ * sizeof(int), stream);
    hipMemsetAsync(e2f_sm, 0, (size_t)NR_ * sizeof(float), stream);

    dim3 trb(32, 8);
    k_tr<<<dim3(10, 4, 1), trb, 0, stream>>>(ent_W, entWt, D, WD);        // [100][300] -> [300][100]
    k_tr<<<dim3(19, 4, 1), trb, 0, stream>>>(rel_W, relWt, D, 2 * WD);    // [100][600] -> [600][100]
    k_tr<<<dim3(10, 13, 1), trb, 0, stream>>>(lstm_Wih, WihT, G4, WD);    // [400][300] -> [300][400]
    k_tr<<<dim3(4, 13, 1), trb, 0, stream>>>(lstm_Whh, WhhT, G4, D);      // [400][100] -> [100][400]
    k_tr<<<dim3(4, 4, 3), trb, 0, stream>>>(head_W, headWt, D, D);
    k_tr<<<dim3(4, 4, 3), trb, 0, stream>>>(self_W, selfWt, D, D);
    k_tr<<<dim3(4, 4, 3), trb, 0, stream>>>(tail_W, tailWt, D, D);
    k_tr<<<dim3(10, 4, 3), trb, 0, stream>>>(e2e_W, e2eWt, D, 3 * D);     // per-l [100][300] -> [300][100]
    k_bihh<<<1, 512, 0, stream>>>(lstm_bih, lstm_bhh, bihh);

    k_hist<<<(NF + 255) / 256, 256, 0, stream>>>(f2e, cnt);
    k_scan<<<1, 256, 0, stream>>>(cnt, off, cursor);
    k_scatter<<<(NF + 255) / 256, 256, 0, stream>>>(f2e, cursor, sorted);
    k_cntf<<<(NR_ + 255) / 256, 256, 0, stream>>>(off, cnt_f);

    // xW = word_emb[qtext] @ WihT + (bih+bhh)   (160 rows, 400 cols)
    k_gemm<WD, 0><<<dim3(5, 4), 256, 0, stream>>>(word_emb, WihT, bihh, qtext, xW, G4, B * Q);
    k_lstm<<<B, 512, 0, stream>>>(xW, WhhT, qh);
    k_q2e<<<dim3(B, 3), 128, 0, stream>>>(qh, q2e_W, q2e_b, q2e_vec);

    // rel_proj = rel_emb @ relWt + rel_b   (301 rows)
    k_gemm<2 * WD, 0><<<dim3(10, 1), 256, 0, stream>>>(rel_emb, relWt, rel_b, nullptr, rel_proj, D, NREL);
    for (int l = 0; l < 3; ++l)
        k_gemm<D, 0><<<dim3(10, 1), 256, 0, stream>>>(rel_proj, selfWt + l * D * D, self_b + l * D,
                                                      nullptr, self_proj + l * NREL * D, D, NREL);

    k_wf_rel<<<dim3(2, B), 256, 0, stream>>>(qtext, qh, rel_proj, Wf_rel);
    k_wmax<<<B, 256, 0, stream>>>(Wf_rel, kb_rel, Wmax);
    k_wt_rel<<<dim3(2, B), 256, 0, stream>>>(Wf_rel, Wmax, Wt_rel);
    k_e2fsm<<<(NF + 255) / 256, 256, 0, stream>>>(Wt_rel, kb_rel, e2f, W_tilde, e2f_sm);

    // lee = entity_emb[local_entity] @ entWt + ent_b
    k_gemm<WD, 0><<<dim3(NR_ / 32, 1), 256, 0, stream>>>(entity_emb, entWt, ent_b, local_entity,
                                                         leeA, D, NR_);

    float* cur = leeA; float* nxt = leeB;
    for (int l = 0; l < 3; ++l) {
        k_gemm_dual<<<NR_ / 32, 256, 0, stream>>>(cur, headWt + l * D * D, head_b + l * D, head,
                                                  selfWt + l * D * D, self_b + l * D, lee_self);
        k_gather<<<NR_ / 4, 256, 0, stream>>>(sorted, off, W_tilde, pr, e2f_sm, kb_rel, e2f,
                                              self_proj, head, l, u_buf, pr_acc);
        k_tailent<<<NR_ / 32, 256, 0, stream>>>(u_buf, cnt_f, tailWt + l * D * D, tail_b + l * D,
                                                cur, lee_self, q2e_vec + l * B * D,
                                                e2eWt + l * WD * D, e2e_b + l * D,
                                                pr_acc, pr, nxt);
        float* tmp = cur; cur = nxt; nxt = tmp;
    }
    k_score<<<(B * E + 255) / 256, 256, 0, stream>>>(local_entity, cur, score_W, score_b, (float*)d_out);
}